// Round 6
// baseline (127.208 us; speedup 1.0000x reference)
//
#include <hip/hip_runtime.h>

#define DD 128
#define BM 64
#define CHUNK 2          // tiles per block -> 128 contiguous rows/block, grid 1024
#define T_TYPES 16

typedef __bf16 bf16x8 __attribute__((ext_vector_type(8)));
typedef float  f32x4  __attribute__((ext_vector_type(4)));

// Build the MFMA B-fragment image of w[t] (fp32 [128][128]) into Bs (bf16,
// fragment order). Fragment granule F = ((nt*4+kk)*64 + lane), 16B each;
// lane(q,n16) of fragment (nt,kk) holds B[k=kk*32+q*8+j][n=nt*16+n16].
// Wave-level access: at fixed (i,j) the 64 lanes read 4 rows x 64B contiguous
// segments -> coalesced, L2-served (w[t] is 64KB, shared by ~64 blocks).
__device__ __forceinline__ void build_B(const float* __restrict__ wt,
                                        __bf16* __restrict__ Bs, int tid) {
    #pragma unroll
    for (int i = 0; i < 8; ++i) {
        int F    = tid + (i << 8);
        int lane = F & 63;
        int kk   = (F >> 6) & 3;
        int nt   = F >> 8;
        int q    = lane >> 4;
        int n16  = lane & 15;
        const float* p = wt + (kk * 32 + q * 8) * DD + nt * 16 + n16;
        bf16x8 v;
        #pragma unroll
        for (int j = 0; j < 8; ++j) v[j] = (__bf16)p[j * DD];
        *(bf16x8*)&Bs[(size_t)F * 8] = v;
    }
}

// ---------- Fused kernel: no pre-pass, no workspace ----------
// A-fragments loaded DIRECTLY from global in MFMA layout (no LDS round-trip).
// LDS = Bs only (32 KB). launch_bounds(256,4) -> whole 1024-block grid
// co-resident. W fragments built per-block from fp32 w (L2-resident).
__global__ __launch_bounds__(256, 4) void hetero_fused_kernel(
    const float* __restrict__ x,
    const int*   __restrict__ tv,
    const float* __restrict__ w,      // [T][128][128] fp32
    const float* __restrict__ bias,   // [T][128]
    float*       __restrict__ out)    // [N][128]
{
    __shared__ __bf16 Bs[DD * DD];       // 32 KB, fragment order

    const int tid  = threadIdx.x;
    const int wave = tid >> 6;
    const int lane = tid & 63;
    const int q    = lane >> 4;
    const int n16  = lane & 15;
    const int chunk0 = blockIdx.x * (BM * CHUNK);

    int t_res = tv[chunk0];

    // ---- x tile 0 prefetch FIRST: HBM latency hides under the W build ----
    f32x4 xlo[4], xhi[4];
    {
        const float* base = x + (size_t)(chunk0 + wave * 16 + n16) * DD + q * 8;
        #pragma unroll
        for (int kk = 0; kk < 4; ++kk) {
            xlo[kk] = *(const f32x4*)(base + kk * 32);
            xhi[kk] = *(const f32x4*)(base + kk * 32 + 4);
        }
    }

    // ---- W[t_res] -> Bs (in-block transpose+convert, L2-served) ----
    build_B(w + (size_t)t_res * DD * DD, Bs, tid);

    // bias cached in regs for resident type
    float bv[8];
    #pragma unroll
    for (int nt = 0; nt < 8; ++nt) bv[nt] = bias[t_res * DD + nt * 16 + n16];

    __syncthreads();   // all waves' Bs granules written before any wave reads

    #pragma unroll
    for (int tile = 0; tile < CHUNK; ++tile) {
        const int trow0 = chunk0 + tile * BM;
        const int wrow0 = trow0 + wave * 16;

        // issue next tile's prefetch first -> loads fly under this tile's compute
        f32x4 nlo[4], nhi[4];
        if (tile + 1 < CHUNK) {
            const float* base = x + (size_t)(wrow0 + BM + n16) * DD + q * 8;
            #pragma unroll
            for (int kk = 0; kk < 4; ++kk) {
                nlo[kk] = *(const f32x4*)(base + kk * 32);
                nhi[kk] = *(const f32x4*)(base + kk * 32 + 4);
            }
        }

        // pack A fragments: A[m=n16][k=kk*32+q*8+j]
        bf16x8 a[4];
        #pragma unroll
        for (int kk = 0; kk < 4; ++kk) {
            bf16x8 t;
            t[0] = (__bf16)xlo[kk][0]; t[1] = (__bf16)xlo[kk][1];
            t[2] = (__bf16)xlo[kk][2]; t[3] = (__bf16)xlo[kk][3];
            t[4] = (__bf16)xhi[kk][0]; t[5] = (__bf16)xhi[kk][1];
            t[6] = (__bf16)xhi[kk][2]; t[7] = (__bf16)xhi[kk][3];
            a[kk] = t;
        }

        const int tlo = tv[trow0];
        const int thi = tv[trow0 + BM - 1];

        for (int t = tlo; t <= thi; ++t) {
            if (t != t_res) {               // rare: block-uniform branch (~15/1024 blocks)
                __syncthreads();            // all waves done reading old Bs
                build_B(w + (size_t)t * DD * DD, Bs, tid);
                t_res = t;
                #pragma unroll
                for (int nt = 0; nt < 8; ++nt) bv[nt] = bias[t * DD + nt * 16 + n16];
                __syncthreads();
            }

            f32x4 acc[8];
            #pragma unroll
            for (int nt = 0; nt < 8; ++nt) acc[nt] = (f32x4){0.f, 0.f, 0.f, 0.f};

            #pragma unroll
            for (int nt = 0; nt < 8; ++nt) {
                #pragma unroll
                for (int kk = 0; kk < 4; ++kk) {
                    bf16x8 b = *(const bf16x8*)&Bs[(((nt << 2) | kk) << 9) | (lane << 3)];
                    acc[nt] = __builtin_amdgcn_mfma_f32_16x16x32_bf16(a[kk], b, acc[nt], 0, 0, 0);
                }
            }

            // epilogue: D[row=q*4+reg][col=nt*16+n16]; 4x64B segments per store,
            // adjacent nt pairs merge into full 128B lines in L2.
            const int rbase = wrow0 + q * 4;
            bool m0 = true, m1 = true, m2 = true, m3 = true;
            if (tlo != thi) {
                m0 = (tv[rbase + 0] == t);
                m1 = (tv[rbase + 1] == t);
                m2 = (tv[rbase + 2] == t);
                m3 = (tv[rbase + 3] == t);
            }
            float* o = out + (size_t)rbase * DD + n16;
            #pragma unroll
            for (int nt = 0; nt < 8; ++nt) {
                float* oc = o + nt * 16;
                if (m0) oc[0 * DD] = acc[nt][0] + bv[nt];
                if (m1) oc[1 * DD] = acc[nt][1] + bv[nt];
                if (m2) oc[2 * DD] = acc[nt][2] + bv[nt];
                if (m3) oc[3 * DD] = acc[nt][3] + bv[nt];
            }
        }

        // hand prefetch buffer over
        #pragma unroll
        for (int kk = 0; kk < 4; ++kk) { xlo[kk] = nlo[kk]; xhi[kk] = nhi[kk]; }
    }
}

extern "C" void kernel_launch(void* const* d_in, const int* in_sizes, int n_in,
                              void* d_out, int out_size, void* d_ws, size_t ws_size,
                              hipStream_t stream) {
    const float* x    = (const float*)d_in[0];
    const int*   tv   = (const int*)d_in[1];
    const float* w    = (const float*)d_in[2];
    const float* bias = (const float*)d_in[3];
    float*       out  = (float*)d_out;

    int nrows = in_sizes[0] / DD;                  // 131072
    int grid  = nrows / (BM * CHUNK);              // 1024

    hipLaunchKernelGGL(hetero_fused_kernel, dim3(grid), dim3(256), 0, stream,
                       x, tv, w, bias, out);
}